// Round 1
// baseline (315.513 us; speedup 1.0000x reference)
//
#include <hip/hip_runtime.h>
#include <math.h>

#define BB   1024
#define DD   768
#define HIDV 384
#define MLPH 300
#define MLPP 320   // padded to multiple of 64

__device__ __forceinline__ float softplusf(float x) {
    return (x > 20.f) ? x : log1pf(expf(x));
}

__device__ __forceinline__ void f4arr(float4 v, float* o) {
    o[0] = v.x; o[1] = v.y; o[2] = v.z; o[3] = v.w;
}

// ---------------- init: zero accumulators (accum[16] + sumexp[1024]) ----------------
__global__ void k_init(float* __restrict__ ws) {
    int i = blockIdx.x * 256 + threadIdx.x;
    if (i < 16 + BB) ws[i] = 0.f;
}

// ---------------- A: z1/z2 reduce + sample + KL partial ----------------
// thread handles (b, q): 4 consecutive h = 4q..4q+3, q in [0,96)
__global__ __launch_bounds__(256) void k_sample(
    const float* __restrict__ zl, const float* __restrict__ zv,
    const float* __restrict__ wl, const float* __restrict__ blp,
    const float* __restrict__ wv, const float* __restrict__ bvp,
    const float* __restrict__ eps1, const float* __restrict__ eps2,
    float* __restrict__ s1, float* __restrict__ s2, float* __restrict__ accum)
{
    int g = blockIdx.x * 256 + threadIdx.x;
    int b = g / 96;
    int q = g - b * 96;
    const float4* zl4 = (const float4*)zl;
    const float4* zv4 = (const float4*)zv;

    float m1[4] = {0,0,0,0}, t1[4] = {0,0,0,0};
    float m2[4] = {0,0,0,0}, t2[4] = {0,0,0,0};

    int base1 = b * (20 * 192) + q;
    #pragma unroll
    for (int s = 0; s < 20; ++s) {
        float w = wl[s];
        float a[4], c[4];
        f4arr(zl4[base1 + s * 192], a);
        f4arr(zl4[base1 + s * 192 + 96], c);
        #pragma unroll
        for (int j = 0; j < 4; ++j) {
            m1[j] = fmaf(a[j], w, m1[j]);
            t1[j] = fmaf(c[j], w, t1[j]);
        }
    }
    int base2 = b * (36 * 192) + q;
    #pragma unroll
    for (int s = 0; s < 36; ++s) {
        float w = wv[s];
        float a[4], c[4];
        f4arr(zv4[base2 + s * 192], a);
        f4arr(zv4[base2 + s * 192 + 96], c);
        #pragma unroll
        for (int j = 0; j < 4; ++j) {
            m2[j] = fmaf(a[j], w, m2[j]);
            t2[j] = fmaf(c[j], w, t2[j]);
        }
    }

    float bl = blp[0], bv = bvp[0];
    float e1v[4], e2v[4];
    f4arr(((const float4*)eps1)[b * 96 + q], e1v);
    f4arr(((const float4*)eps2)[b * 96 + q], e2v);

    float s1o[4], s2o[4];
    float con = 0.f;
    #pragma unroll
    for (int j = 0; j < 4; ++j) {
        float mu1 = m1[j] + bl;
        float sg1 = softplusf(t1[j] + bl) + 1e-7f;
        float mu2 = m2[j] + bv;
        float sg2 = softplusf(t2[j] + bv) + 1e-7f;
        float e1 = e1v[j], e2 = e2v[j];
        float sv1 = fmaf(sg1, e1, mu1);
        float sv2 = fmaf(sg2, e2, mu2);
        s1o[j] = sv1; s2o[j] = sv2;
        float z12 = (sv1 - mu2) / sg2;
        float z21 = (sv2 - mu1) / sg1;
        con += -0.5f * (e1 * e1 + e2 * e2) + 0.5f * z12 * z12 + 0.5f * z21 * z21;
    }
    ((float4*)s1)[b * 96 + q] = make_float4(s1o[0], s1o[1], s1o[2], s1o[3]);
    ((float4*)s2)[b * 96 + q] = make_float4(s2o[0], s2o[1], s2o[2], s2o[3]);

    // block reduce con -> atomicAdd
    #pragma unroll
    for (int m = 1; m < 64; m <<= 1) con += __shfl_xor(con, m);
    __shared__ float pr[4];
    if ((threadIdx.x & 63) == 0) pr[threadIdx.x >> 6] = con;
    __syncthreads();
    if (threadIdx.x == 0) atomicAdd(&accum[0], pr[0] + pr[1] + pr[2] + pr[3]);
}

// ---------------- B: Axb = s1 @ W1x^T + b1 (padded), By = s2 @ W1y^T ----------------
__global__ __launch_bounds__(256) void k_gemm(
    const float* __restrict__ s1, const float* __restrict__ s2,
    const float* __restrict__ W1, const float* __restrict__ b1,
    float* __restrict__ Axb, float* __restrict__ By)
{
    __shared__ __align__(16) float Ss[32][68];
    __shared__ __align__(16) float Ws[32][68];
    int z = blockIdx.z;
    const float* S = z ? s2 : s1;
    float* Out = z ? By : Axb;
    int wofs = z ? HIDV : 0;
    int b0 = blockIdx.x * 64;
    int k0 = blockIdx.y * 64;
    int tid = threadIdx.x;
    int r = tid >> 2;          // 0..63
    int c4 = tid & 3;          // 0..3
    int tx = tid & 15, ty = tid >> 4;

    float4 ps[2], pw[2];
    int krow = k0 + r;
    auto ld = [&](int hc) {
        #pragma unroll
        for (int u = 0; u < 2; ++u) {
            int hq = (c4 + 4 * u) * 4;   // 0..28
            ps[u] = *(const float4*)&S[(b0 + r) * HIDV + hc + hq];
            pw[u] = (krow < MLPH) ? *(const float4*)&W1[krow * DD + wofs + hc + hq]
                                  : make_float4(0.f, 0.f, 0.f, 0.f);
        }
    };
    ld(0);
    float acc[4][4] = {{0.f}};
    for (int ch = 0; ch < 12; ++ch) {
        __syncthreads();
        #pragma unroll
        for (int u = 0; u < 2; ++u) {
            int hq = (c4 + 4 * u) * 4;
            Ss[hq + 0][r] = ps[u].x; Ss[hq + 1][r] = ps[u].y;
            Ss[hq + 2][r] = ps[u].z; Ss[hq + 3][r] = ps[u].w;
            Ws[hq + 0][r] = pw[u].x; Ws[hq + 1][r] = pw[u].y;
            Ws[hq + 2][r] = pw[u].z; Ws[hq + 3][r] = pw[u].w;
        }
        __syncthreads();
        if (ch < 11) ld((ch + 1) * 32);
        #pragma unroll
        for (int h = 0; h < 32; ++h) {
            float sv[4], wv4[4];
            f4arr(*(const float4*)&Ss[h][ty * 4], sv);
            f4arr(*(const float4*)&Ws[h][tx * 4], wv4);
            #pragma unroll
            for (int i = 0; i < 4; ++i)
                #pragma unroll
                for (int j = 0; j < 4; ++j)
                    acc[i][j] = fmaf(sv[i], wv4[j], acc[i][j]);
        }
    }
    #pragma unroll
    for (int i = 0; i < 4; ++i) {
        int bb = b0 + ty * 4 + i;
        float o[4];
        #pragma unroll
        for (int j = 0; j < 4; ++j) {
            int k = k0 + tx * 4 + j;
            float v = acc[i][j];
            if (!z) v += b1[k < MLPH ? k : 0];
            o[j] = (k < MLPH) ? v : 0.f;
        }
        *(float4*)&Out[bb * MLPP + k0 + tx * 4] = make_float4(o[0], o[1], o[2], o[3]);
    }
}

// ---------------- C: T0 sum ----------------
__global__ void k_t0(const float* __restrict__ Axb, const float* __restrict__ By,
                     const float* __restrict__ W2, const float* __restrict__ b2,
                     float* __restrict__ accum)
{
    int b = blockIdx.x;
    int l = threadIdx.x;  // 64
    float t = 0.f;
    for (int k = l; k < MLPH; k += 64)
        t = fmaf(fmaxf(Axb[b * MLPP + k] + By[b * MLPP + k], 0.f), W2[k], t);
    #pragma unroll
    for (int m = 1; m < 64; m <<= 1) t += __shfl_xor(t, m);
    if (l == 0) atomicAdd(&accum[1], softplusf(t + b2[0]));
}

// ---------------- D: pair kernel, fused sumexp(T1) over j ----------------
__global__ __launch_bounds__(256) void k_pairs(
    const float* __restrict__ Axb, const float* __restrict__ By,
    const int* __restrict__ perm, const float* __restrict__ W2,
    const float* __restrict__ b2, float* __restrict__ sumexp)
{
    __shared__ __align__(16) float As[64][68];   // [k][j]
    __shared__ __align__(16) float Bs[64][68];   // [k][i]
    __shared__ float w2s[MLPP];
    int tid = threadIdx.x;
    int j0 = blockIdx.x * 64;
    int i0 = blockIdx.y * 64;
    for (int t = tid; t < MLPP; t += 256) w2s[t] = (t < MLPH) ? W2[t] : 0.f;
    int r = tid >> 2;          // 0..63
    int c4 = tid & 3;
    int tx = tid & 15, ty = tid >> 4;
    int prow = perm[i0 + r];

    float4 pa[4], pb[4];
    auto ld = [&](int kc) {
        #pragma unroll
        for (int u = 0; u < 4; ++u) {
            int kq = (c4 + 4 * u) * 4;   // 0..60
            pa[u] = *(const float4*)&Axb[(j0 + r) * MLPP + kc + kq];
            pb[u] = *(const float4*)&By[prow * MLPP + kc + kq];
        }
    };
    ld(0);
    float acc[4][4] = {{0.f}};  // [i_c][j_d]
    for (int ch = 0; ch < 5; ++ch) {
        __syncthreads();
        #pragma unroll
        for (int u = 0; u < 4; ++u) {
            int kq = (c4 + 4 * u) * 4;
            As[kq + 0][r] = pa[u].x; As[kq + 1][r] = pa[u].y;
            As[kq + 2][r] = pa[u].z; As[kq + 3][r] = pa[u].w;
            Bs[kq + 0][r] = pb[u].x; Bs[kq + 1][r] = pb[u].y;
            Bs[kq + 2][r] = pb[u].z; Bs[kq + 3][r] = pb[u].w;
        }
        __syncthreads();
        if (ch < 4) ld((ch + 1) * 64);
        int kc = ch * 64;
        #pragma unroll
        for (int k = 0; k < 64; ++k) {
            float w = w2s[kc + k];
            float avv[4], bvv[4];
            f4arr(*(const float4*)&As[k][tx * 4], avv);
            f4arr(*(const float4*)&Bs[k][ty * 4], bvv);
            #pragma unroll
            for (int c = 0; c < 4; ++c)
                #pragma unroll
                for (int d = 0; d < 4; ++d)
                    acc[c][d] = fmaf(fmaxf(avv[d] + bvv[c], 0.f), w, acc[c][d]);
        }
    }
    float b2v = b2[0];
    #pragma unroll
    for (int c = 0; c < 4; ++c) {
        float ssum = 0.f;
        #pragma unroll
        for (int d = 0; d < 4; ++d) {
            // exp(softplus(x)) == 1 + exp(x)
            ssum += 1.f + expf(acc[c][d] + b2v);
        }
        ssum += __shfl_xor(ssum, 1);
        ssum += __shfl_xor(ssum, 2);
        ssum += __shfl_xor(ssum, 4);
        ssum += __shfl_xor(ssum, 8);
        if (tx == 0) atomicAdd(&sumexp[i0 + ty * 4 + c], ssum);
    }
}

// ---------------- E: final scalar ----------------
__global__ __launch_bounds__(256) void k_final(
    const float* __restrict__ accum, const float* __restrict__ sumexp,
    float* __restrict__ out)
{
    int tid = threadIdx.x;
    float s = 0.f;
    for (int i = tid; i < BB; i += 256) s += logf(sumexp[i]);
    #pragma unroll
    for (int m = 1; m < 64; m <<= 1) s += __shfl_xor(s, m);
    __shared__ float red[4];
    if ((tid & 63) == 0) red[tid >> 6] = s;
    __syncthreads();
    if (tid == 0) {
        float lse_mean = (red[0] + red[1] + red[2] + red[3]) / (float)BB;
        float d_skl = accum[0] / (2.f * (float)BB);
        float t0_mean = accum[1] / (float)BB;
        float lower = t0_mean - (lse_mean - logf((float)BB));
        out[0] = d_skl - lower;
    }
}

extern "C" void kernel_launch(void* const* d_in, const int* in_sizes, int n_in,
                              void* d_out, int out_size, void* d_ws, size_t ws_size,
                              hipStream_t stream)
{
    const float* zl     = (const float*)d_in[0];
    const float* zv     = (const float*)d_in[1];
    const float* fc_l_w = (const float*)d_in[2];
    const float* fc_l_b = (const float*)d_in[3];
    const float* fc_v_w = (const float*)d_in[4];
    const float* fc_v_b = (const float*)d_in[5];
    const float* W1     = (const float*)d_in[6];
    const float* b1     = (const float*)d_in[7];
    const float* W2     = (const float*)d_in[8];
    const float* b2     = (const float*)d_in[9];
    const float* eps1   = (const float*)d_in[10];
    const float* eps2   = (const float*)d_in[11];
    const int*   perm   = (const int*)d_in[12];
    float* out = (float*)d_out;

    float* ws     = (float*)d_ws;
    float* accum  = ws;                    // 16
    float* sumexp = ws + 16;               // 1024
    float* s1     = ws + 16 + BB;          // B*384
    float* s2     = s1 + BB * HIDV;        // B*384
    float* Axb    = s2 + BB * HIDV;        // B*320
    float* By     = Axb + BB * MLPP;       // B*320

    k_init<<<5, 256, 0, stream>>>(ws);
    k_sample<<<(BB * 96) / 256, 256, 0, stream>>>(zl, zv, fc_l_w, fc_l_b, fc_v_w, fc_v_b,
                                                  eps1, eps2, s1, s2, accum);
    k_gemm<<<dim3(16, 5, 2), 256, 0, stream>>>(s1, s2, W1, b1, Axb, By);
    k_t0<<<BB, 64, 0, stream>>>(Axb, By, W2, b2, accum);
    k_pairs<<<dim3(16, 16), 256, 0, stream>>>(Axb, By, perm, W2, b2, sumexp);
    k_final<<<1, 256, 0, stream>>>(accum, sumexp, out);
}

// Round 2
// 313.854 us; speedup vs baseline: 1.0053x; 1.0053x over previous
//
#include <hip/hip_runtime.h>
#include <math.h>

#define BB   1024
#define DD   768
#define HIDV 384
#define MLPH 300
#define MLPP 320   // padded to multiple of 64

__device__ __forceinline__ float softplusf(float x) {
    return (x > 20.f) ? x : log1pf(expf(x));
}

__device__ __forceinline__ void f4arr(float4 v, float* o) {
    o[0] = v.x; o[1] = v.y; o[2] = v.z; o[3] = v.w;
}

// ---------------- init: zero accumulators (accum[16] + sumexp[1024]) ----------------
__global__ void k_init(float* __restrict__ ws) {
    int i = blockIdx.x * 256 + threadIdx.x;
    if (i < 16 + BB) ws[i] = 0.f;
}

// ---------------- A: fused z-reduce + sample + KL partial ----------------
// One block (192 threads) per batch row. Thread t owns float4 column group t
// (cols 4t..4t+3 of the 768-wide z row) and reduces over s for BOTH tensors.
// All 56 loads per thread are independent -> deep memory-level parallelism.
// Threads 96..191 own the sigma half; exchange through LDS; threads 0..95
// then compute s1/s2 + KL contributions entirely in-register.
__global__ __launch_bounds__(192, 3) void k_rs(
    const float* __restrict__ zl, const float* __restrict__ zv,
    const float* __restrict__ wl, const float* __restrict__ blp,
    const float* __restrict__ wv, const float* __restrict__ bvp,
    const float* __restrict__ eps1, const float* __restrict__ eps2,
    float* __restrict__ s1, float* __restrict__ s2, float* __restrict__ accum)
{
    int b = blockIdx.x;
    int t = threadIdx.x;               // 0..191
    const float4* zl4 = (const float4*)zl + b * (20 * 192) + t;
    const float4* zv4 = (const float4*)zv + b * (36 * 192) + t;

    float z1v[4] = {0,0,0,0}, z2v[4] = {0,0,0,0};
    #pragma unroll
    for (int s = 0; s < 20; ++s) {
        float w = wl[s];
        float a[4];
        f4arr(zl4[s * 192], a);
        #pragma unroll
        for (int j = 0; j < 4; ++j) z1v[j] = fmaf(a[j], w, z1v[j]);
    }
    #pragma unroll
    for (int s = 0; s < 36; ++s) {
        float w = wv[s];
        float a[4];
        f4arr(zv4[s * 192], a);
        #pragma unroll
        for (int j = 0; j < 4; ++j) z2v[j] = fmaf(a[j], w, z2v[j]);
    }

    float bl = blp[0], bv = bvp[0];

    __shared__ __align__(16) float sg1s[HIDV];  // softplus(z1_sig)+eps
    __shared__ __align__(16) float sg2s[HIDV];

    if (t >= 96) {
        float o1[4], o2[4];
        #pragma unroll
        for (int j = 0; j < 4; ++j) {
            o1[j] = softplusf(z1v[j] + bl) + 1e-7f;
            o2[j] = softplusf(z2v[j] + bv) + 1e-7f;
        }
        ((float4*)sg1s)[t - 96] = make_float4(o1[0], o1[1], o1[2], o1[3]);
        ((float4*)sg2s)[t - 96] = make_float4(o2[0], o2[1], o2[2], o2[3]);
    }
    __syncthreads();

    float con = 0.f;
    if (t < 96) {
        float e1v[4], e2v[4], g1[4], g2[4];
        f4arr(((const float4*)eps1)[b * 96 + t], e1v);
        f4arr(((const float4*)eps2)[b * 96 + t], e2v);
        f4arr(((const float4*)sg1s)[t], g1);
        f4arr(((const float4*)sg2s)[t], g2);
        float s1o[4], s2o[4];
        #pragma unroll
        for (int j = 0; j < 4; ++j) {
            float mu1 = z1v[j] + bl;
            float mu2 = z2v[j] + bv;
            float sg1 = g1[j], sg2 = g2[j];
            float e1 = e1v[j], e2 = e2v[j];
            float sv1 = fmaf(sg1, e1, mu1);
            float sv2 = fmaf(sg2, e2, mu2);
            s1o[j] = sv1; s2o[j] = sv2;
            float z12 = (sv1 - mu2) / sg2;
            float z21 = (sv2 - mu1) / sg1;
            con += -0.5f * (e1 * e1 + e2 * e2) + 0.5f * z12 * z12 + 0.5f * z21 * z21;
        }
        ((float4*)s1)[b * 96 + t] = make_float4(s1o[0], s1o[1], s1o[2], s1o[3]);
        ((float4*)s2)[b * 96 + t] = make_float4(s2o[0], s2o[1], s2o[2], s2o[3]);
    }

    #pragma unroll
    for (int m = 1; m < 64; m <<= 1) con += __shfl_xor(con, m);
    __shared__ float pr[3];
    if ((t & 63) == 0) pr[t >> 6] = con;
    __syncthreads();
    if (t == 0) atomicAdd(&accum[0], pr[0] + pr[1] + pr[2]);
}

// ---------------- B: Axb = s1 @ W1x^T + b1 (padded), By = s2 @ W1y^T ----------------
__global__ __launch_bounds__(256) void k_gemm(
    const float* __restrict__ s1, const float* __restrict__ s2,
    const float* __restrict__ W1, const float* __restrict__ b1,
    float* __restrict__ Axb, float* __restrict__ By)
{
    __shared__ __align__(16) float Ss[32][68];
    __shared__ __align__(16) float Ws[32][68];
    int z = blockIdx.z;
    const float* S = z ? s2 : s1;
    float* Out = z ? By : Axb;
    int wofs = z ? HIDV : 0;
    int b0 = blockIdx.x * 64;
    int k0 = blockIdx.y * 64;
    int tid = threadIdx.x;
    int r = tid >> 2;          // 0..63
    int c4 = tid & 3;          // 0..3
    int tx = tid & 15, ty = tid >> 4;

    float4 ps[2], pw[2];
    int krow = k0 + r;
    auto ld = [&](int hc) {
        #pragma unroll
        for (int u = 0; u < 2; ++u) {
            int hq = (c4 + 4 * u) * 4;   // 0..28
            ps[u] = *(const float4*)&S[(b0 + r) * HIDV + hc + hq];
            pw[u] = (krow < MLPH) ? *(const float4*)&W1[krow * DD + wofs + hc + hq]
                                  : make_float4(0.f, 0.f, 0.f, 0.f);
        }
    };
    ld(0);
    float acc[4][4] = {{0.f}};
    for (int ch = 0; ch < 12; ++ch) {
        __syncthreads();
        #pragma unroll
        for (int u = 0; u < 2; ++u) {
            int hq = (c4 + 4 * u) * 4;
            Ss[hq + 0][r] = ps[u].x; Ss[hq + 1][r] = ps[u].y;
            Ss[hq + 2][r] = ps[u].z; Ss[hq + 3][r] = ps[u].w;
            Ws[hq + 0][r] = pw[u].x; Ws[hq + 1][r] = pw[u].y;
            Ws[hq + 2][r] = pw[u].z; Ws[hq + 3][r] = pw[u].w;
        }
        __syncthreads();
        if (ch < 11) ld((ch + 1) * 32);
        #pragma unroll
        for (int h = 0; h < 32; ++h) {
            float sv[4], wv4[4];
            f4arr(*(const float4*)&Ss[h][ty * 4], sv);
            f4arr(*(const float4*)&Ws[h][tx * 4], wv4);
            #pragma unroll
            for (int i = 0; i < 4; ++i)
                #pragma unroll
                for (int j = 0; j < 4; ++j)
                    acc[i][j] = fmaf(sv[i], wv4[j], acc[i][j]);
        }
    }
    #pragma unroll
    for (int i = 0; i < 4; ++i) {
        int bb = b0 + ty * 4 + i;
        float o[4];
        #pragma unroll
        for (int j = 0; j < 4; ++j) {
            int k = k0 + tx * 4 + j;
            float v = acc[i][j];
            if (!z) v += b1[k < MLPH ? k : 0];
            o[j] = (k < MLPH) ? v : 0.f;
        }
        *(float4*)&Out[bb * MLPP + k0 + tx * 4] = make_float4(o[0], o[1], o[2], o[3]);
    }
}

// ---------------- C: T0 sum ----------------
__global__ void k_t0(const float* __restrict__ Axb, const float* __restrict__ By,
                     const float* __restrict__ W2, const float* __restrict__ b2,
                     float* __restrict__ accum)
{
    int b = blockIdx.x;
    int l = threadIdx.x;  // 64
    float t = 0.f;
    for (int k = l; k < MLPH; k += 64)
        t = fmaf(fmaxf(Axb[b * MLPP + k] + By[b * MLPP + k], 0.f), W2[k], t);
    #pragma unroll
    for (int m = 1; m < 64; m <<= 1) t += __shfl_xor(t, m);
    if (l == 0) atomicAdd(&accum[1], softplusf(t + b2[0]));
}

// ---------------- D: pair kernel, fused sumexp(T1) over j ----------------
__global__ __launch_bounds__(256) void k_pairs(
    const float* __restrict__ Axb, const float* __restrict__ By,
    const int* __restrict__ perm, const float* __restrict__ W2,
    const float* __restrict__ b2, float* __restrict__ sumexp)
{
    __shared__ __align__(16) float As[64][68];   // [k][j]
    __shared__ __align__(16) float Bs[64][68];   // [k][i]
    __shared__ float w2s[MLPP];
    int tid = threadIdx.x;
    int j0 = blockIdx.x * 64;
    int i0 = blockIdx.y * 64;
    for (int t = tid; t < MLPP; t += 256) w2s[t] = (t < MLPH) ? W2[t] : 0.f;
    int r = tid >> 2;          // 0..63
    int c4 = tid & 3;
    int tx = tid & 15, ty = tid >> 4;
    int prow = perm[i0 + r];

    float4 pa[4], pb[4];
    auto ld = [&](int kc) {
        #pragma unroll
        for (int u = 0; u < 4; ++u) {
            int kq = (c4 + 4 * u) * 4;   // 0..60
            pa[u] = *(const float4*)&Axb[(j0 + r) * MLPP + kc + kq];
            pb[u] = *(const float4*)&By[prow * MLPP + kc + kq];
        }
    };
    ld(0);
    float acc[4][4] = {{0.f}};  // [i_c][j_d]
    for (int ch = 0; ch < 5; ++ch) {
        __syncthreads();
        #pragma unroll
        for (int u = 0; u < 4; ++u) {
            int kq = (c4 + 4 * u) * 4;
            As[kq + 0][r] = pa[u].x; As[kq + 1][r] = pa[u].y;
            As[kq + 2][r] = pa[u].z; As[kq + 3][r] = pa[u].w;
            Bs[kq + 0][r] = pb[u].x; Bs[kq + 1][r] = pb[u].y;
            Bs[kq + 2][r] = pb[u].z; Bs[kq + 3][r] = pb[u].w;
        }
        __syncthreads();
        if (ch < 4) ld((ch + 1) * 64);
        int kc = ch * 64;
        #pragma unroll
        for (int k = 0; k < 64; ++k) {
            float w = w2s[kc + k];
            float avv[4], bvv[4];
            f4arr(*(const float4*)&As[k][tx * 4], avv);
            f4arr(*(const float4*)&Bs[k][ty * 4], bvv);
            #pragma unroll
            for (int c = 0; c < 4; ++c)
                #pragma unroll
                for (int d = 0; d < 4; ++d)
                    acc[c][d] = fmaf(fmaxf(avv[d] + bvv[c], 0.f), w, acc[c][d]);
        }
    }
    float b2v = b2[0];
    #pragma unroll
    for (int c = 0; c < 4; ++c) {
        float ssum = 0.f;
        #pragma unroll
        for (int d = 0; d < 4; ++d) {
            // exp(softplus(x)) == 1 + exp(x)
            ssum += 1.f + expf(acc[c][d] + b2v);
        }
        ssum += __shfl_xor(ssum, 1);
        ssum += __shfl_xor(ssum, 2);
        ssum += __shfl_xor(ssum, 4);
        ssum += __shfl_xor(ssum, 8);
        if (tx == 0) atomicAdd(&sumexp[i0 + ty * 4 + c], ssum);
    }
}

// ---------------- E: final scalar ----------------
__global__ __launch_bounds__(256) void k_final(
    const float* __restrict__ accum, const float* __restrict__ sumexp,
    float* __restrict__ out)
{
    int tid = threadIdx.x;
    float s = 0.f;
    for (int i = tid; i < BB; i += 256) s += logf(sumexp[i]);
    #pragma unroll
    for (int m = 1; m < 64; m <<= 1) s += __shfl_xor(s, m);
    __shared__ float red[4];
    if ((tid & 63) == 0) red[tid >> 6] = s;
    __syncthreads();
    if (tid == 0) {
        float lse_mean = (red[0] + red[1] + red[2] + red[3]) / (float)BB;
        float d_skl = accum[0] / (2.f * (float)BB);
        float t0_mean = accum[1] / (float)BB;
        float lower = t0_mean - (lse_mean - logf((float)BB));
        out[0] = d_skl - lower;
    }
}

extern "C" void kernel_launch(void* const* d_in, const int* in_sizes, int n_in,
                              void* d_out, int out_size, void* d_ws, size_t ws_size,
                              hipStream_t stream)
{
    const float* zl     = (const float*)d_in[0];
    const float* zv     = (const float*)d_in[1];
    const float* fc_l_w = (const float*)d_in[2];
    const float* fc_l_b = (const float*)d_in[3];
    const float* fc_v_w = (const float*)d_in[4];
    const float* fc_v_b = (const float*)d_in[5];
    const float* W1     = (const float*)d_in[6];
    const float* b1     = (const float*)d_in[7];
    const float* W2     = (const float*)d_in[8];
    const float* b2     = (const float*)d_in[9];
    const float* eps1   = (const float*)d_in[10];
    const float* eps2   = (const float*)d_in[11];
    const int*   perm   = (const int*)d_in[12];
    float* out = (float*)d_out;

    float* ws     = (float*)d_ws;
    float* accum  = ws;                    // 16
    float* sumexp = ws + 16;               // 1024
    float* s1     = ws + 16 + BB;          // B*384
    float* s2     = s1 + BB * HIDV;        // B*384
    float* Axb    = s2 + BB * HIDV;        // B*320
    float* By     = Axb + BB * MLPP;       // B*320

    k_init<<<5, 256, 0, stream>>>(ws);
    k_rs<<<BB, 192, 0, stream>>>(zl, zv, fc_l_w, fc_l_b, fc_v_w, fc_v_b,
                                 eps1, eps2, s1, s2, accum);
    k_gemm<<<dim3(16, 5, 2), 256, 0, stream>>>(s1, s2, W1, b1, Axb, By);
    k_t0<<<BB, 64, 0, stream>>>(Axb, By, W2, b2, accum);
    k_pairs<<<dim3(16, 16), 256, 0, stream>>>(Axb, By, perm, W2, b2, sumexp);
    k_final<<<1, 256, 0, stream>>>(accum, sumexp, out);
}

// Round 3
// 313.087 us; speedup vs baseline: 1.0077x; 1.0024x over previous
//
#include <hip/hip_runtime.h>
#include <math.h>

#define BB   1024
#define DD   768
#define HIDV 384
#define MLPH 300
#define MLPP 320   // padded to multiple of 64

__device__ __forceinline__ float softplusf(float x) {
    return (x > 20.f) ? x : log1pf(expf(x));
}

__device__ __forceinline__ void f4arr(float4 v, float* o) {
    o[0] = v.x; o[1] = v.y; o[2] = v.z; o[3] = v.w;
}

// ---------------- init: zero accumulators (accum[16] + sumexp[1024]) ----------------
__global__ void k_init(float* __restrict__ ws) {
    int i = blockIdx.x * 256 + threadIdx.x;
    if (i < 16 + BB) ws[i] = 0.f;
}

// ---------------- A: fused z-reduce + sample + KL partial ----------------
// One block (192 threads) per batch row. Thread t owns float4 column group t.
// The 56 loads (20 zl + 36 zv) stream through a 16-deep rotating register
// FIFO, fully unrolled -> ~16 outstanding global_load_dwordx4 per wave.
// Loads complete in order, so consuming the oldest entry waits only on its
// own vmcnt slot.
__global__ __launch_bounds__(192, 4) void k_rs(
    const float* __restrict__ zl, const float* __restrict__ zv,
    const float* __restrict__ wl, const float* __restrict__ blp,
    const float* __restrict__ wv, const float* __restrict__ bvp,
    const float* __restrict__ eps1, const float* __restrict__ eps2,
    float* __restrict__ s1, float* __restrict__ s2, float* __restrict__ accum)
{
    int b = blockIdx.x;
    int t = threadIdx.x;               // 0..191
    const float4* zl4 = (const float4*)zl + b * (20 * 192) + t;
    const float4* zv4 = (const float4*)zv + b * (36 * 192) + t;

    float z1v[4] = {0,0,0,0}, z2v[4] = {0,0,0,0};

    float4 r[16];
    // prologue: fill the FIFO (stream index i: 0..19 -> zl, 20..55 -> zv)
    #pragma unroll
    for (int i = 0; i < 16; ++i)
        r[i] = (i < 20) ? zl4[i * 192] : zv4[(i - 20) * 192];
    // steady state: consume oldest, refill
    #pragma unroll
    for (int i = 0; i < 56; ++i) {
        float a[4];
        f4arr(r[i & 15], a);
        if (i + 16 < 56)
            r[i & 15] = (i + 16 < 20) ? zl4[(i + 16) * 192] : zv4[(i - 4) * 192];
        if (i < 20) {
            float w = wl[i];
            #pragma unroll
            for (int j = 0; j < 4; ++j) z1v[j] = fmaf(a[j], w, z1v[j]);
        } else {
            float w = wv[i - 20];
            #pragma unroll
            for (int j = 0; j < 4; ++j) z2v[j] = fmaf(a[j], w, z2v[j]);
        }
    }

    float bl = blp[0], bv = bvp[0];

    __shared__ __align__(16) float sg1s[HIDV];  // softplus(z1_sig)+eps
    __shared__ __align__(16) float sg2s[HIDV];

    if (t >= 96) {
        float o1[4], o2[4];
        #pragma unroll
        for (int j = 0; j < 4; ++j) {
            o1[j] = softplusf(z1v[j] + bl) + 1e-7f;
            o2[j] = softplusf(z2v[j] + bv) + 1e-7f;
        }
        ((float4*)sg1s)[t - 96] = make_float4(o1[0], o1[1], o1[2], o1[3]);
        ((float4*)sg2s)[t - 96] = make_float4(o2[0], o2[1], o2[2], o2[3]);
    }
    __syncthreads();

    float con = 0.f;
    if (t < 96) {
        float e1v[4], e2v[4], g1[4], g2[4];
        f4arr(((const float4*)eps1)[b * 96 + t], e1v);
        f4arr(((const float4*)eps2)[b * 96 + t], e2v);
        f4arr(((const float4*)sg1s)[t], g1);
        f4arr(((const float4*)sg2s)[t], g2);
        float s1o[4], s2o[4];
        #pragma unroll
        for (int j = 0; j < 4; ++j) {
            float mu1 = z1v[j] + bl;
            float mu2 = z2v[j] + bv;
            float sg1 = g1[j], sg2 = g2[j];
            float e1 = e1v[j], e2 = e2v[j];
            float sv1 = fmaf(sg1, e1, mu1);
            float sv2 = fmaf(sg2, e2, mu2);
            s1o[j] = sv1; s2o[j] = sv2;
            float z12 = (sv1 - mu2) / sg2;
            float z21 = (sv2 - mu1) / sg1;
            con += -0.5f * (e1 * e1 + e2 * e2) + 0.5f * z12 * z12 + 0.5f * z21 * z21;
        }
        ((float4*)s1)[b * 96 + t] = make_float4(s1o[0], s1o[1], s1o[2], s1o[3]);
        ((float4*)s2)[b * 96 + t] = make_float4(s2o[0], s2o[1], s2o[2], s2o[3]);
    }

    #pragma unroll
    for (int m = 1; m < 64; m <<= 1) con += __shfl_xor(con, m);
    __shared__ float pr[3];
    if ((t & 63) == 0) pr[t >> 6] = con;
    __syncthreads();
    if (t == 0) atomicAdd(&accum[0], pr[0] + pr[1] + pr[2]);
}

// ---------------- B: Axb = s1 @ W1x^T + b1 (padded), By = s2 @ W1y^T ----------------
__global__ __launch_bounds__(256) void k_gemm(
    const float* __restrict__ s1, const float* __restrict__ s2,
    const float* __restrict__ W1, const float* __restrict__ b1,
    float* __restrict__ Axb, float* __restrict__ By)
{
    __shared__ __align__(16) float Ss[32][68];
    __shared__ __align__(16) float Ws[32][68];
    int z = blockIdx.z;
    const float* S = z ? s2 : s1;
    float* Out = z ? By : Axb;
    int wofs = z ? HIDV : 0;
    int b0 = blockIdx.x * 64;
    int k0 = blockIdx.y * 64;
    int tid = threadIdx.x;
    int r = tid >> 2;          // 0..63
    int c4 = tid & 3;          // 0..3
    int tx = tid & 15, ty = tid >> 4;

    float4 ps[2], pw[2];
    int krow = k0 + r;
    auto ld = [&](int hc) {
        #pragma unroll
        for (int u = 0; u < 2; ++u) {
            int hq = (c4 + 4 * u) * 4;   // 0..28
            ps[u] = *(const float4*)&S[(b0 + r) * HIDV + hc + hq];
            pw[u] = (krow < MLPH) ? *(const float4*)&W1[krow * DD + wofs + hc + hq]
                                  : make_float4(0.f, 0.f, 0.f, 0.f);
        }
    };
    ld(0);
    float acc[4][4] = {{0.f}};
    for (int ch = 0; ch < 12; ++ch) {
        __syncthreads();
        #pragma unroll
        for (int u = 0; u < 2; ++u) {
            int hq = (c4 + 4 * u) * 4;
            Ss[hq + 0][r] = ps[u].x; Ss[hq + 1][r] = ps[u].y;
            Ss[hq + 2][r] = ps[u].z; Ss[hq + 3][r] = ps[u].w;
            Ws[hq + 0][r] = pw[u].x; Ws[hq + 1][r] = pw[u].y;
            Ws[hq + 2][r] = pw[u].z; Ws[hq + 3][r] = pw[u].w;
        }
        __syncthreads();
        if (ch < 11) ld((ch + 1) * 32);
        #pragma unroll
        for (int h = 0; h < 32; ++h) {
            float sv[4], wv4[4];
            f4arr(*(const float4*)&Ss[h][ty * 4], sv);
            f4arr(*(const float4*)&Ws[h][tx * 4], wv4);
            #pragma unroll
            for (int i = 0; i < 4; ++i)
                #pragma unroll
                for (int j = 0; j < 4; ++j)
                    acc[i][j] = fmaf(sv[i], wv4[j], acc[i][j]);
        }
    }
    #pragma unroll
    for (int i = 0; i < 4; ++i) {
        int bb = b0 + ty * 4 + i;
        float o[4];
        #pragma unroll
        for (int j = 0; j < 4; ++j) {
            int k = k0 + tx * 4 + j;
            float v = acc[i][j];
            if (!z) v += b1[k < MLPH ? k : 0];
            o[j] = (k < MLPH) ? v : 0.f;
        }
        *(float4*)&Out[bb * MLPP + k0 + tx * 4] = make_float4(o[0], o[1], o[2], o[3]);
    }
}

// ---------------- C: T0 sum ----------------
__global__ void k_t0(const float* __restrict__ Axb, const float* __restrict__ By,
                     const float* __restrict__ W2, const float* __restrict__ b2,
                     float* __restrict__ accum)
{
    int b = blockIdx.x;
    int l = threadIdx.x;  // 64
    float t = 0.f;
    for (int k = l; k < MLPH; k += 64)
        t = fmaf(fmaxf(Axb[b * MLPP + k] + By[b * MLPP + k], 0.f), W2[k], t);
    #pragma unroll
    for (int m = 1; m < 64; m <<= 1) t += __shfl_xor(t, m);
    if (l == 0) atomicAdd(&accum[1], softplusf(t + b2[0]));
}

// ---------------- D: pair kernel, fused sumexp(T1) over j ----------------
__global__ __launch_bounds__(256) void k_pairs(
    const float* __restrict__ Axb, const float* __restrict__ By,
    const int* __restrict__ perm, const float* __restrict__ W2,
    const float* __restrict__ b2, float* __restrict__ sumexp)
{
    __shared__ __align__(16) float As[64][68];   // [k][j]
    __shared__ __align__(16) float Bs[64][68];   // [k][i]
    __shared__ float w2s[MLPP];
    int tid = threadIdx.x;
    int j0 = blockIdx.x * 64;
    int i0 = blockIdx.y * 64;
    for (int t = tid; t < MLPP; t += 256) w2s[t] = (t < MLPH) ? W2[t] : 0.f;
    int r = tid >> 2;          // 0..63
    int c4 = tid & 3;
    int tx = tid & 15, ty = tid >> 4;
    int prow = perm[i0 + r];

    float4 pa[4], pb[4];
    auto ld = [&](int kc) {
        #pragma unroll
        for (int u = 0; u < 4; ++u) {
            int kq = (c4 + 4 * u) * 4;   // 0..60
            pa[u] = *(const float4*)&Axb[(j0 + r) * MLPP + kc + kq];
            pb[u] = *(const float4*)&By[prow * MLPP + kc + kq];
        }
    };
    ld(0);
    float acc[4][4] = {{0.f}};  // [i_c][j_d]
    for (int ch = 0; ch < 5; ++ch) {
        __syncthreads();
        #pragma unroll
        for (int u = 0; u < 4; ++u) {
            int kq = (c4 + 4 * u) * 4;
            As[kq + 0][r] = pa[u].x; As[kq + 1][r] = pa[u].y;
            As[kq + 2][r] = pa[u].z; As[kq + 3][r] = pa[u].w;
            Bs[kq + 0][r] = pb[u].x; Bs[kq + 1][r] = pb[u].y;
            Bs[kq + 2][r] = pb[u].z; Bs[kq + 3][r] = pb[u].w;
        }
        __syncthreads();
        if (ch < 4) ld((ch + 1) * 64);
        int kc = ch * 64;
        #pragma unroll
        for (int k = 0; k < 64; ++k) {
            float w = w2s[kc + k];
            float avv[4], bvv[4];
            f4arr(*(const float4*)&As[k][tx * 4], avv);
            f4arr(*(const float4*)&Bs[k][ty * 4], bvv);
            #pragma unroll
            for (int c = 0; c < 4; ++c)
                #pragma unroll
                for (int d = 0; d < 4; ++d)
                    acc[c][d] = fmaf(fmaxf(avv[d] + bvv[c], 0.f), w, acc[c][d]);
        }
    }
    float b2v = b2[0];
    #pragma unroll
    for (int c = 0; c < 4; ++c) {
        float ssum = 0.f;
        #pragma unroll
        for (int d = 0; d < 4; ++d) {
            // exp(softplus(x)) == 1 + exp(x)
            ssum += 1.f + expf(acc[c][d] + b2v);
        }
        ssum += __shfl_xor(ssum, 1);
        ssum += __shfl_xor(ssum, 2);
        ssum += __shfl_xor(ssum, 4);
        ssum += __shfl_xor(ssum, 8);
        if (tx == 0) atomicAdd(&sumexp[i0 + ty * 4 + c], ssum);
    }
}

// ---------------- E: final scalar ----------------
__global__ __launch_bounds__(256) void k_final(
    const float* __restrict__ accum, const float* __restrict__ sumexp,
    float* __restrict__ out)
{
    int tid = threadIdx.x;
    float s = 0.f;
    for (int i = tid; i < BB; i += 256) s += logf(sumexp[i]);
    #pragma unroll
    for (int m = 1; m < 64; m <<= 1) s += __shfl_xor(s, m);
    __shared__ float red[4];
    if ((tid & 63) == 0) red[tid >> 6] = s;
    __syncthreads();
    if (tid == 0) {
        float lse_mean = (red[0] + red[1] + red[2] + red[3]) / (float)BB;
        float d_skl = accum[0] / (2.f * (float)BB);
        float t0_mean = accum[1] / (float)BB;
        float lower = t0_mean - (lse_mean - logf((float)BB));
        out[0] = d_skl - lower;
    }
}

extern "C" void kernel_launch(void* const* d_in, const int* in_sizes, int n_in,
                              void* d_out, int out_size, void* d_ws, size_t ws_size,
                              hipStream_t stream)
{
    const float* zl     = (const float*)d_in[0];
    const float* zv     = (const float*)d_in[1];
    const float* fc_l_w = (const float*)d_in[2];
    const float* fc_l_b = (const float*)d_in[3];
    const float* fc_v_w = (const float*)d_in[4];
    const float* fc_v_b = (const float*)d_in[5];
    const float* W1     = (const float*)d_in[6];
    const float* b1     = (const float*)d_in[7];
    const float* W2     = (const float*)d_in[8];
    const float* b2     = (const float*)d_in[9];
    const float* eps1   = (const float*)d_in[10];
    const float* eps2   = (const float*)d_in[11];
    const int*   perm   = (const int*)d_in[12];
    float* out = (float*)d_out;

    float* ws     = (float*)d_ws;
    float* accum  = ws;                    // 16
    float* sumexp = ws + 16;               // 1024
    float* s1     = ws + 16 + BB;          // B*384
    float* s2     = s1 + BB * HIDV;        // B*384
    float* Axb    = s2 + BB * HIDV;        // B*320
    float* By     = Axb + BB * MLPP;       // B*320

    k_init<<<5, 256, 0, stream>>>(ws);
    k_rs<<<BB, 192, 0, stream>>>(zl, zv, fc_l_w, fc_l_b, fc_v_w, fc_v_b,
                                 eps1, eps2, s1, s2, accum);
    k_gemm<<<dim3(16, 5, 2), 256, 0, stream>>>(s1, s2, W1, b1, Axb, By);
    k_t0<<<BB, 64, 0, stream>>>(Axb, By, W2, b2, accum);
    k_pairs<<<dim3(16, 16), 256, 0, stream>>>(Axb, By, perm, W2, b2, sumexp);
    k_final<<<1, 256, 0, stream>>>(accum, sumexp, out);
}